// Round 4
// baseline (122.377 us; speedup 1.0000x reference)
//
#include <hip/hip_runtime.h>
#include <hip/hip_bf16.h>
#include <math.h>

// B=1024, F=4096, D=32: s = data@embed, out = sigmoid(gb + data@bias + ||s||^2)
//
// R9: R8 with the workspace-aliasing bug fixed. R8's absmax=1.0 was unwritten rows:
// ws_b/ctr were offset by 64*KS*MT floats but ws_s occupies 64*KS*MT*D_DIM floats,
// so partial stores for mt>=4 clobbered the atomic counters -> finalize never fired
// for those tiles. Pure pointer bug; the split-K last-arriver-finalizes design is
// unchanged and gets its clean test here.
//  - KS=8 x MT=16: grid 512 x 4 waves; waves split K, partials 1MB.
//  - after fence+atomicAdd(ctr[mt]), the 8th arriver finalizes its 16 rows inline.
//  - ctr zeroed by a 256B hipMemsetAsync on-stream (graph-capturable).
//  - bid mapping mt=bid&63, ks=bid>>6: all 8 producers + finisher share bid%8 ->
//    same XCD under round-robin dispatch -> partials exchange in one L2.

#define F_DIM 4096
#define D_DIM 32
#define B_DIM 1024
#define MT 16               // rows per block (one MFMA M-tile)
#define KS 8                // cross-block K splits
#define KC 512              // k per block
#define KW 128              // k per wave (4 MFMA k-steps)
#define LDB 520             // shorts per LDS row (1040B stride, 16B-aligned)

typedef __attribute__((ext_vector_type(8))) short short8;   // MFMA A/B frag (8 bf16)
typedef __attribute__((ext_vector_type(4))) float f32x4;    // MFMA C/D frag

__device__ inline unsigned int pkbf(float a, float b) {     // 2x fp32 -> packed bf16 (RNE)
    __hip_bfloat162 h = __float22bfloat162_rn(make_float2(a, b));
    union { __hip_bfloat162 h2; unsigned int u; } c; c.h2 = h;
    return c.u;   // low 16 = a, high 16 = b
}

__device__ inline short8 as_short8(uint4 u) {
    union { uint4 v; short8 s; } c; c.v = u; return c.s;
}

__global__ __launch_bounds__(256, 4) void fm_fused(const float* __restrict__ data,
                                                   const float* __restrict__ embed,
                                                   const float* __restrict__ bias,
                                                   const float* __restrict__ gbias,
                                                   float* __restrict__ ws_s,
                                                   float* __restrict__ ws_b,
                                                   unsigned int* __restrict__ ctr,
                                                   float* __restrict__ out)
{
    __shared__ short lBT[33][LDB];            // rows 0..31: embed^T bf16, row 32: bias (33.5 KB)
    __shared__ float redCT[4][3][16][20];     // C frags [w][nt][col][row]           (15 KB)
    __shared__ int   shLast;

    const int t  = threadIdx.x;
    const int w  = t >> 6;                    // wave 0..3 -> k-slab [w*KW, w*KW+KW)
    const int l  = t & 63;
    const int mt = blockIdx.x & 63;           // M-tile 0..63  (same mt => same bid%8 => same XCD)
    const int ks = blockIdx.x >> 6;           // K-split 0..7
    const int m0 = mt * MT;
    const int kb = ks * KC;

    // ---- stage B^T: thread owns d-pair (t&15)*2, walks 4 k-octets of 8 ----
    {
        const int d2  = (t & 15) * 2;
        const int k8b = (t >> 4) * 8;
        #pragma unroll
        for (int ko = 0; ko < 4; ++ko) {
            const int k8 = k8b + ko * 128;
            const float* ep = embed + (size_t)(kb + k8) * D_DIM + d2;
            float2 e[8];
            #pragma unroll
            for (int j = 0; j < 8; ++j) e[j] = *(const float2*)(ep + (size_t)j * D_DIM);
            uint4 ux, uy;
            ux.x = pkbf(e[0].x, e[1].x); ux.y = pkbf(e[2].x, e[3].x);
            ux.z = pkbf(e[4].x, e[5].x); ux.w = pkbf(e[6].x, e[7].x);
            uy.x = pkbf(e[0].y, e[1].y); uy.y = pkbf(e[2].y, e[3].y);
            uy.z = pkbf(e[4].y, e[5].y); uy.w = pkbf(e[6].y, e[7].y);
            *(uint4*)(&lBT[d2    ][k8]) = ux; // ds_write_b128, 16B-aligned
            *(uint4*)(&lBT[d2 + 1][k8]) = uy;
        }
    }
    // ---- stage bias row (bf16) as B-row 32: threads 0..63, 8 k each ----
    if (t < 64) {
        const float4 b0 = *(const float4*)(bias + kb + t * 8);
        const float4 b1 = *(const float4*)(bias + kb + t * 8 + 4);
        uint4 u;
        u.x = pkbf(b0.x, b0.y); u.y = pkbf(b0.z, b0.w);
        u.z = pkbf(b1.x, b1.y); u.w = pkbf(b1.z, b1.w);
        *(uint4*)(&lBT[32][t * 8]) = u;
    }
    __syncthreads();

    // ---- MFMA: A direct from global (R7-verified layout: lane holds row l&15,
    //      k = quad*8..+7). Wave w covers k in [kb+w*KW, kb+w*KW+KW), 4 steps.
    const int quad = l >> 4;
    const int c    = l & 15;
    const float* arow = data + (size_t)(m0 + c) * F_DIM + kb + w * KW;

    f32x4 acc0 = {0.f, 0.f, 0.f, 0.f};        // d = 0..15
    f32x4 acc1 = {0.f, 0.f, 0.f, 0.f};        // d = 16..31
    f32x4 acc2 = {0.f, 0.f, 0.f, 0.f};        // col 0 = bias term
    #pragma unroll
    for (int s = 0; s < 4; ++s) {
        const int kw = s * 32 + quad * 8;      // within wave slab
        const int kk = w * KW + kw;            // within block tile
        const float4 x0 = *(const float4*)(arow + kw);
        const float4 x1 = *(const float4*)(arow + kw + 4);
        uint4 ua;
        ua.x = pkbf(x0.x, x0.y); ua.y = pkbf(x0.z, x0.w);
        ua.z = pkbf(x1.x, x1.y); ua.w = pkbf(x1.z, x1.w);
        const short8 a  = as_short8(ua);
        const short8 b0 = *(const short8*)(&lBT[c     ][kk]);
        const short8 b1 = *(const short8*)(&lBT[16 + c][kk]);
        const short8 b2 = *(const short8*)(&lBT[32    ][kk]);  // broadcast: all lanes same addr
        acc0 = __builtin_amdgcn_mfma_f32_16x16x32_bf16(a, b0, acc0, 0, 0, 0);
        acc1 = __builtin_amdgcn_mfma_f32_16x16x32_bf16(a, b1, acc1, 0, 0, 0);
        acc2 = __builtin_amdgcn_mfma_f32_16x16x32_bf16(a, b2, acc2, 0, 0, 0);
    }

    // ---- cross-wave K-reduce via LDS (R0-verified pattern).
    //      C layout: row=quad*4+j, col=c; store transposed [col][row].
    *(f32x4*)(&redCT[w][0][c][quad * 4]) = acc0;
    *(f32x4*)(&redCT[w][1][c][quad * 4]) = acc1;
    *(f32x4*)(&redCT[w][2][c][quad * 4]) = acc2;
    __syncthreads();

    // ---- combine 4 waves, store block partial: ws_s[mt][ks][r][d], ws_b[mt][ks][r]
    #pragma unroll
    for (int h = 0; h < 2; ++h) {
        const int e  = t + h * 256;            // 512 outputs: (nt, r, cc)
        const int nt = e >> 8;
        const int r  = (e >> 4) & 15;
        const int cc = e & 15;
        const float v = redCT[0][nt][cc][r] + redCT[1][nt][cc][r]
                      + redCT[2][nt][cc][r] + redCT[3][nt][cc][r];
        ws_s[((size_t)(mt * KS + ks) * MT + r) * D_DIM + nt * 16 + cc] = v;
    }
    if (t < 16) {
        const float vb = redCT[0][2][0][t] + redCT[1][2][0][t]
                       + redCT[2][2][0][t] + redCT[3][2][0][t];
        ws_b[(size_t)(mt * KS + ks) * MT + t] = vb;
    }

    // ---- completion: every thread fences its writes, then one atomic per block ----
    __threadfence();
    __syncthreads();
    if (t == 0) {
        const unsigned int old = atomicAdd(ctr + mt, 1u);
        shLast = (old == KS - 1);
    }
    __syncthreads();
    if (!shLast) return;
    __threadfence();                           // acquire side

    // ---- finalize this M-tile's 16 rows (partials L2-hot, same XCD) ----
    {
        const int r  = t >> 4;                 // 0..15
        const int i  = t & 15;                 // d-pair index
        const int d2 = i * 2;
        float sx = 0.f, sy = 0.f;
        #pragma unroll
        for (int k2 = 0; k2 < KS; ++k2) {
            const float2 p = *(const float2*)(ws_s + ((size_t)(mt * KS + k2) * MT + r) * D_DIM + d2);
            sx += p.x; sy += p.y;
        }
        float val = sx * sx + sy * sy;         // partial ||s||^2 over 2 d
        val += __shfl_xor(val, 1);  val += __shfl_xor(val, 2);
        val += __shfl_xor(val, 4);  val += __shfl_xor(val, 8);
        if (i == 0) {
            float bs = 0.f;
            #pragma unroll
            for (int k2 = 0; k2 < KS; ++k2) bs += ws_b[(size_t)(mt * KS + k2) * MT + r];
            const float x = gbias[0] + bs + val;
            out[m0 + r] = 1.0f / (1.0f + __expf(-x));
        }
    }
}

extern "C" void kernel_launch(void* const* d_in, const int* in_sizes, int n_in,
                              void* d_out, int out_size, void* d_ws, size_t ws_size,
                              hipStream_t stream) {
    const float* data  = (const float*)d_in[0];
    const float* embed = (const float*)d_in[1];
    const float* bias  = (const float*)d_in[2];
    const float* gb    = (const float*)d_in[3];
    float* out  = (float*)d_out;

    // Layout (R8 bug fix): ws_s = 64*KS*MT*D_DIM floats (1 MB), THEN ws_b (32 KB), THEN ctr.
    float* ws_s = (float*)d_ws;
    float* ws_b = ws_s + (size_t)64 * KS * MT * D_DIM;            // 64*8*16*32 = 262144 floats
    unsigned int* ctr = (unsigned int*)(ws_b + (size_t)64 * KS * MT);  // after 8192 floats

    hipMemsetAsync(ctr, 0, 64 * sizeof(unsigned int), stream);

    dim3 grid(64 * KS);      // 512 blocks: mt = bid&63, ks = bid>>6
    dim3 block(256);
    fm_fused<<<grid, block, 0, stream>>>(data, embed, bias, gb, ws_s, ws_b, ctr, out);
}

// Round 5
// 72.615 us; speedup vs baseline: 1.6853x; 1.6853x over previous
//
#include <hip/hip_runtime.h>
#include <hip/hip_bf16.h>
#include <math.h>

// B=1024, F=4096, D=32: s = data@embed, out = sigmoid(gb + data@bias + ||s||^2)
//
// R10: revert to R7's proven two-kernel structure (71.1us); R8/R9's fused atomic
// finalize is refuted (kernel alone 65us: 2 blocks/CU with 4x per-block staging +
// device-scope threadfence L2 writebacks; MfmaUtil 0.2%, VALUBusy 1% = pure stall).
// Budget model (triangulated R0/R2/R4): 43.2us harness fill + ~12-14us launch gaps
// + kernels (~14-18us in R7). Only the kernel part is claw-able; it is latency-bound.
// Changes vs R7, all aimed at latency hiding:
//  - KS=64, KC=64: grid 1024 = 4 blocks/CU (was 2), 16 waves/CU. LDS 4.8KB.
//  - all 256 threads stage B^T (thread = d-pair x k-quad, 4x float2 -> ds_write_b64),
//    halving the per-thread staging chain.
//  - A float4 prefetch ISSUED BEFORE staging: vmcnt entries survive the barrier, so
//    A's HBM latency hides under embed staging + sync (T14 issue-early).
//  - bias as broadcast 33rd B-row (R9-verified: every C col = bias dot; col 0 used).
// fm_final adapted to KS=64: 8 independent float4 loads/lane, verified xor-reduce.

#define F_DIM 4096
#define D_DIM 32
#define B_DIM 1024
#define MT 64               // rows per block = 16 per wave x 4 waves
#define KS 64               // K splits
#define KC 64               // k per block
#define LDB 72              // shorts per LDS row: 144B stride (16B-aligned)

typedef __attribute__((ext_vector_type(8))) short short8;   // MFMA A/B frag (8 bf16)
typedef __attribute__((ext_vector_type(4))) float f32x4;    // MFMA C/D frag

__device__ inline unsigned int pkbf(float a, float b) {     // 2x fp32 -> packed bf16 (RNE)
    __hip_bfloat162 h = __float22bfloat162_rn(make_float2(a, b));
    union { __hip_bfloat162 h2; unsigned int u; } c; c.h2 = h;
    return c.u;   // low 16 = a, high 16 = b
}

__device__ inline short8 as_short8(uint4 u) {
    union { uint4 v; short8 s; } c; c.v = u; return c.s;
}

__global__ __launch_bounds__(256, 4) void fm_gemm(const float* __restrict__ data,
                                                  const float* __restrict__ embed,
                                                  const float* __restrict__ bias,
                                                  float* __restrict__ ws_s,
                                                  float* __restrict__ ws_b)
{
    __shared__ short lBT[33][LDB];            // rows 0..31: embed^T bf16, row 32: bias (4.8 KB)

    const int t  = threadIdx.x;
    const int w  = t >> 6;                    // wave 0..3 -> rows [w*16, w*16+16)
    const int l  = t & 63;
    const int mt = blockIdx.x >> 6;           // M-tile 0..15
    const int ks = blockIdx.x & 63;           // K-split 0..63
    const int m0 = mt * MT;
    const int kb = ks * KC;

    // ---- A prefetch: issue the 4 global float4 loads FIRST (latency hides under
    //      staging + barrier; vmcnt is preserved across s_barrier).
    const int quad = l >> 4;
    const int c    = l & 15;
    const float* arow = data + (size_t)(m0 + w * 16 + c) * F_DIM + kb;
    float4 x00 = *(const float4*)(arow + quad * 8);
    float4 x01 = *(const float4*)(arow + quad * 8 + 4);
    float4 x10 = *(const float4*)(arow + 32 + quad * 8);
    float4 x11 = *(const float4*)(arow + 32 + quad * 8 + 4);

    // ---- stage B^T: thread owns d-pair (t&15)*2 and k-quad (t>>4)*4 (all 256 busy)
    {
        const int d2 = (t & 15) * 2;
        const int k4 = (t >> 4) * 4;          // 0..60
        const float* ep = embed + (size_t)(kb + k4) * D_DIM + d2;
        float2 e0 = *(const float2*)(ep);
        float2 e1 = *(const float2*)(ep + D_DIM);
        float2 e2 = *(const float2*)(ep + 2 * D_DIM);
        float2 e3 = *(const float2*)(ep + 3 * D_DIM);
        uint2 ux, uy;
        ux.x = pkbf(e0.x, e1.x); ux.y = pkbf(e2.x, e3.x);
        uy.x = pkbf(e0.y, e1.y); uy.y = pkbf(e2.y, e3.y);
        *(uint2*)(&lBT[d2    ][k4]) = ux;     // ds_write_b64, 8B-aligned
        *(uint2*)(&lBT[d2 + 1][k4]) = uy;
    }
    // ---- stage bias row (bf16) as broadcast B-row 32: threads 0..7, 8 k each ----
    if (t < 8) {
        const float4 b0 = *(const float4*)(bias + kb + t * 8);
        const float4 b1 = *(const float4*)(bias + kb + t * 8 + 4);
        uint4 u;
        u.x = pkbf(b0.x, b0.y); u.y = pkbf(b0.z, b0.w);
        u.z = pkbf(b1.x, b1.y); u.w = pkbf(b1.z, b1.w);
        *(uint4*)(&lBT[32][t * 8]) = u;
    }
    __syncthreads();

    // ---- MFMA: A layout (verified): lane holds row l&15, k = quad*8..+7; 2 k-steps.
    f32x4 acc0 = {0.f, 0.f, 0.f, 0.f};       // d = 0..15
    f32x4 acc1 = {0.f, 0.f, 0.f, 0.f};       // d = 16..31
    f32x4 acc2 = {0.f, 0.f, 0.f, 0.f};       // col 0 = bias term
    {
        uint4 ua;
        ua.x = pkbf(x00.x, x00.y); ua.y = pkbf(x00.z, x00.w);
        ua.z = pkbf(x01.x, x01.y); ua.w = pkbf(x01.z, x01.w);
        const short8 a  = as_short8(ua);
        const int kk = quad * 8;
        const short8 b0 = *(const short8*)(&lBT[c     ][kk]);
        const short8 b1 = *(const short8*)(&lBT[16 + c][kk]);
        const short8 b2 = *(const short8*)(&lBT[32    ][kk]);  // broadcast row
        acc0 = __builtin_amdgcn_mfma_f32_16x16x32_bf16(a, b0, acc0, 0, 0, 0);
        acc1 = __builtin_amdgcn_mfma_f32_16x16x32_bf16(a, b1, acc1, 0, 0, 0);
        acc2 = __builtin_amdgcn_mfma_f32_16x16x32_bf16(a, b2, acc2, 0, 0, 0);
    }
    {
        uint4 ua;
        ua.x = pkbf(x10.x, x10.y); ua.y = pkbf(x10.z, x10.w);
        ua.z = pkbf(x11.x, x11.y); ua.w = pkbf(x11.z, x11.w);
        const short8 a  = as_short8(ua);
        const int kk = 32 + quad * 8;
        const short8 b0 = *(const short8*)(&lBT[c     ][kk]);
        const short8 b1 = *(const short8*)(&lBT[16 + c][kk]);
        const short8 b2 = *(const short8*)(&lBT[32    ][kk]);
        acc0 = __builtin_amdgcn_mfma_f32_16x16x32_bf16(a, b0, acc0, 0, 0, 0);
        acc1 = __builtin_amdgcn_mfma_f32_16x16x32_bf16(a, b1, acc1, 0, 0, 0);
        acc2 = __builtin_amdgcn_mfma_f32_16x16x32_bf16(a, b2, acc2, 0, 0, 0);
    }

    // ---- epilogue: C layout row=quad*4+j, col=c (verified). Store to [row][ks][d].
    const int rbase = m0 + w * 16 + quad * 4;
    #pragma unroll
    for (int j = 0; j < 4; ++j) {
        float* p = ws_s + ((size_t)(rbase + j) * KS + ks) * D_DIM;
        p[c]      = acc0[j];                  // 16 lanes -> one 64B segment
        p[16 + c] = acc1[j];
    }
    if (c == 0) {
        #pragma unroll
        for (int j = 0; j < 4; ++j)
            ws_b[(size_t)(rbase + j) * KS + ks] = acc2[j];
    }
}

// One wave per output row: row's 64x32 K-partials are 8KB contiguous = 8 float4/lane.
__global__ __launch_bounds__(256, 4) void fm_final(const float* __restrict__ ws_s,
                                                   const float* __restrict__ ws_b,
                                                   const float* __restrict__ gbias,
                                                   float* __restrict__ out)
{
    const int t = threadIdx.x;
    const int w = t >> 6;
    const int l = t & 63;
    const int row = blockIdx.x * 4 + w;

    const float4* p4 = (const float4*)(ws_s + (size_t)row * KS * D_DIM);
    float4 v = p4[l];                          // chunk: ks = 8j + (l>>3), d = 4*(l&7)..+3
    #pragma unroll
    for (int j = 1; j < 8; ++j) {
        const float4 u = p4[l + 64 * j];
        v.x += u.x; v.y += u.y; v.z += u.z; v.w += u.w;
    }
    #pragma unroll
    for (int m = 8; m <= 32; m <<= 1) {        // reduce over ks (lanes sharing l&7)
        v.x += __shfl_xor(v.x, m); v.y += __shfl_xor(v.y, m);
        v.z += __shfl_xor(v.z, m); v.w += __shfl_xor(v.w, m);
    }
    float c = 0.f;
    if (l < 8)  c = v.x * v.x + v.y * v.y + v.z * v.z + v.w * v.w;  // lanes 0..7 = d-groups
    c += ws_b[(size_t)row * KS + l];                                // 64 bias partials
    #pragma unroll
    for (int m = 1; m <= 32; m <<= 1) c += __shfl_xor(c, m);
    if (l == 0) {
        const float x = gbias[0] + c;
        out[row] = 1.0f / (1.0f + __expf(-x));
    }
}

extern "C" void kernel_launch(void* const* d_in, const int* in_sizes, int n_in,
                              void* d_out, int out_size, void* d_ws, size_t ws_size,
                              hipStream_t stream) {
    const float* data  = (const float*)d_in[0];
    const float* embed = (const float*)d_in[1];
    const float* bias  = (const float*)d_in[2];
    const float* gb    = (const float*)d_in[3];
    float* out  = (float*)d_out;

    float* ws_s = (float*)d_ws;                                  // 1024*64*32 f = 8 MB
    float* ws_b = ws_s + (size_t)B_DIM * KS * D_DIM;             // 1024*64 f = 256 KB

    dim3 gridA(16 * KS);     // 1024 blocks = 16 M-tiles x 64 K-splits (4/CU)
    dim3 blockA(256);
    fm_gemm<<<gridA, blockA, 0, stream>>>(data, embed, bias, ws_s, ws_b);

    dim3 gridB(B_DIM / 4);   // 256 blocks, one wave per row
    dim3 blockB(256);
    fm_final<<<gridB, blockB, 0, stream>>>(ws_s, ws_b, gb, out);
}

// Round 6
// 72.218 us; speedup vs baseline: 1.6945x; 1.0055x over previous
//
#include <hip/hip_runtime.h>
#include <hip/hip_bf16.h>
#include <math.h>

// B=1024, F=4096, D=32: s = data@embed, out = sigmoid(gb + data@bias + ||s||^2)
//
// R11: R7 (best measured: 71.08us) + ONE added technique: A-tile float4 loads hoisted
// BEFORE the B^T staging phase (T14 issue-early). Rationale: R0/R7/R10 quadrangulation
// shows dur = 43.2us harness fill + ~14us launch machinery + ~14us kernels, and the
// kernel slice is latency- not BW-bound (R10: +4MB ws traffic = +1.5us; everything
// else neutral). In R7 the 8 A-loads sit after __syncthreads; hoisting makes their
// ~500cy HBM latency overlap the embed staging + cvt + barrier explicitly instead of
// relying on LLVM to move loads across the barrier. 32 VGPR held across staging
// (~80 total, under the 128 cap of launch_bounds(256,4); no spill).
// Everything else is byte-for-byte R7: KS=32/KC=128/MT=64, 512 blocks, 4MB ws,
// bias as 33rd B-column, fm_final = R0-verified reducer.

#define F_DIM 4096
#define D_DIM 32
#define B_DIM 1024
#define MT 64               // rows per block = 16 per wave x 4 waves
#define KS 32               // K splits
#define KC 128              // k per block
#define LDB 136             // shorts per LDS row: 272B stride (16B-aligned, even bank spread)
#define NW 4

typedef __attribute__((ext_vector_type(8))) short short8;   // MFMA A/B frag (8 bf16)
typedef __attribute__((ext_vector_type(4))) float f32x4;    // MFMA C/D frag

__device__ inline unsigned int pkbf(float a, float b) {     // 2x fp32 -> packed bf16 (RNE)
    __hip_bfloat162 h = __float22bfloat162_rn(make_float2(a, b));
    union { __hip_bfloat162 h2; unsigned int u; } c; c.h2 = h;
    return c.u;   // low 16 = a, high 16 = b
}

__device__ inline short8 as_short8(uint4 u) {
    union { uint4 v; short8 s; } c; c.v = u; return c.s;
}

__global__ __launch_bounds__(256, 4) void fm_gemm(const float* __restrict__ data,
                                                  const float* __restrict__ embed,
                                                  const float* __restrict__ bias,
                                                  float* __restrict__ ws_s,
                                                  float* __restrict__ ws_b)
{
    // rows 0..31: embed^T (bf16), row 32: bias (bf16), rows 33..47: never written;
    // garbage there only feeds C cols 1..15 of the bias n-tile, which are discarded.
    __shared__ short lBT[48][LDB];                // 12.75 KB

    const int t  = threadIdx.x;
    const int w  = t >> 6;                        // wave 0..3 -> rows [w*16, w*16+16)
    const int l  = t & 63;
    const int mt = blockIdx.x >> 5;               // M-tile 0..15
    const int ks = blockIdx.x & 31;               // K-split 0..31
    const int m0 = mt * MT;
    const int kb = ks * KC;

    // ---- A prefetch: issue ALL 8 global float4 loads FIRST; their HBM latency
    //      hides under the embed staging + cvt + barrier below (T14 issue-early).
    const int quad = l >> 4;
    const int c    = l & 15;
    const float* arow = data + (size_t)(m0 + w * 16 + c) * F_DIM + kb;
    float4 xa0[4], xa1[4];
    #pragma unroll
    for (int s = 0; s < 4; ++s) {
        xa0[s] = *(const float4*)(arow + s * 32 + quad * 8);
        xa1[s] = *(const float4*)(arow + s * 32 + quad * 8 + 4);
    }

    // ---- stage B^T: thread owns d-pair (t&15)*2 and k-octet (t>>4)*8 (exactly 256 slots)
    {
        const int d2 = (t & 15) * 2;
        const int k8 = (t >> 4) * 8;
        const float* ep = embed + (size_t)(kb + k8) * D_DIM + d2;
        float2 e[8];
        #pragma unroll
        for (int j = 0; j < 8; ++j) e[j] = *(const float2*)(ep + (size_t)j * D_DIM);
        uint4 ux, uy;
        ux.x = pkbf(e[0].x, e[1].x); ux.y = pkbf(e[2].x, e[3].x);
        ux.z = pkbf(e[4].x, e[5].x); ux.w = pkbf(e[6].x, e[7].x);
        uy.x = pkbf(e[0].y, e[1].y); uy.y = pkbf(e[2].y, e[3].y);
        uy.z = pkbf(e[4].y, e[5].y); uy.w = pkbf(e[6].y, e[7].y);
        *(uint4*)(&lBT[d2    ][k8]) = ux;         // ds_write_b128, 16B-aligned
        *(uint4*)(&lBT[d2 + 1][k8]) = uy;
    }
    // ---- stage bias row (bf16) as B-column 32: threads 0..15, 8 k each
    if (t < 16) {
        const float4 b0 = *(const float4*)(bias + kb + t * 8);
        const float4 b1 = *(const float4*)(bias + kb + t * 8 + 4);
        uint4 u;
        u.x = pkbf(b0.x, b0.y); u.y = pkbf(b0.z, b0.w);
        u.z = pkbf(b1.x, b1.y); u.w = pkbf(b1.z, b1.w);
        *(uint4*)(&lBT[32][t * 8]) = u;
    }
    __syncthreads();

    // ---- MFMA: A layout (verified): lane holds row l&15, k = quad*8..+7; 4 k-steps.
    f32x4 acc0 = {0.f, 0.f, 0.f, 0.f};           // d = 0..15
    f32x4 acc1 = {0.f, 0.f, 0.f, 0.f};           // d = 16..31
    f32x4 acc2 = {0.f, 0.f, 0.f, 0.f};           // col 0 = bias term
    #pragma unroll
    for (int s = 0; s < 4; ++s) {
        const int kk = s * 32 + quad * 8;
        uint4 ua;
        ua.x = pkbf(xa0[s].x, xa0[s].y); ua.y = pkbf(xa0[s].z, xa0[s].w);
        ua.z = pkbf(xa1[s].x, xa1[s].y); ua.w = pkbf(xa1[s].z, xa1[s].w);
        const short8 a  = as_short8(ua);
        const short8 b0 = *(const short8*)(&lBT[c     ][kk]);
        const short8 b1 = *(const short8*)(&lBT[16 + c][kk]);
        const short8 b2 = *(const short8*)(&lBT[32 + c][kk]);
        acc0 = __builtin_amdgcn_mfma_f32_16x16x32_bf16(a, b0, acc0, 0, 0, 0);
        acc1 = __builtin_amdgcn_mfma_f32_16x16x32_bf16(a, b1, acc1, 0, 0, 0);
        acc2 = __builtin_amdgcn_mfma_f32_16x16x32_bf16(a, b2, acc2, 0, 0, 0);
    }

    // ---- epilogue: C layout row=quad*4+j, col=c (verified R4). Store to [row][ks][d].
    const int rbase = m0 + w * 16 + quad * 4;
    #pragma unroll
    for (int j = 0; j < 4; ++j) {
        float* p = ws_s + ((size_t)(rbase + j) * KS + ks) * D_DIM;
        p[c]      = acc0[j];                      // 16 lanes -> one 64B segment
        p[16 + c] = acc1[j];
    }
    if (c == 0) {
        #pragma unroll
        for (int j = 0; j < 4; ++j)
            ws_b[(size_t)(rbase + j) * KS + ks] = acc2[j];
    }
}

// One wave per output row: row's 32x32 K-partials are 4KB contiguous = one float4/lane.
// (R0-verified, unchanged.)
__global__ __launch_bounds__(256, 4) void fm_final(const float* __restrict__ ws_s,
                                                   const float* __restrict__ ws_b,
                                                   const float* __restrict__ gbias,
                                                   float* __restrict__ out)
{
    const int t = threadIdx.x;
    const int w = t >> 6;
    const int l = t & 63;
    const int row = blockIdx.x * 4 + w;

    float4 v = ((const float4*)(ws_s + (size_t)row * KS * D_DIM))[l];  // lane l: k=l>>3, d=(4l)&31
    #pragma unroll
    for (int m = 8; m <= 32; m <<= 1) {       // reduce over k (lanes sharing l&7)
        v.x += __shfl_xor(v.x, m); v.y += __shfl_xor(v.y, m);
        v.z += __shfl_xor(v.z, m); v.w += __shfl_xor(v.w, m);
    }
    float c = 0.f;
    if (l < 8)  c = v.x * v.x + v.y * v.y + v.z * v.z + v.w * v.w;  // lanes 0..7 = d-groups
    if (l < 32) c += ws_b[(size_t)row * KS + l];                    // 32 bias partials
    #pragma unroll
    for (int m = 1; m <= 32; m <<= 1) c += __shfl_xor(c, m);
    if (l == 0) {
        const float x = gbias[0] + c;
        out[row] = 1.0f / (1.0f + __expf(-x));
    }
}

extern "C" void kernel_launch(void* const* d_in, const int* in_sizes, int n_in,
                              void* d_out, int out_size, void* d_ws, size_t ws_size,
                              hipStream_t stream) {
    const float* data  = (const float*)d_in[0];
    const float* embed = (const float*)d_in[1];
    const float* bias  = (const float*)d_in[2];
    const float* gb    = (const float*)d_in[3];
    float* out  = (float*)d_out;

    float* ws_s = (float*)d_ws;                                  // 1024*32*32 f = 4 MB
    float* ws_b = ws_s + (size_t)B_DIM * KS * D_DIM;             // 1024*32 f

    dim3 gridA(16 * KS);     // 512 blocks = 16 M-tiles x 32 K-splits
    dim3 blockA(256);
    fm_gemm<<<gridA, blockA, 0, stream>>>(data, embed, bias, ws_s, ws_b);

    dim3 gridB(B_DIM / 4);   // 256 blocks, one wave per row
    dim3 blockB(256);
    fm_final<<<gridB, blockB, 0, stream>>>(ws_s, ws_b, gb, out);
}